// Round 1
// baseline (142.344 us; speedup 1.0000x reference)
//
#include <hip/hip_runtime.h>
#include <limits.h>
#include <stdint.h>

#define ALPHA 0.2f
#define HALFA 0.1f
static constexpr int N = 8192;
static constexpr int D = 128;
static constexpr int C = 512;
static constexpr int MAXG = 64;                   // e-list capacity (Poisson(16), >8 sigma)
static constexpr int FT = 64;                     // term1 tile (c and j)
static constexpr int NT1 = (C / FT) * (N / FT);   // 8*128 = 1024 term1 blocks
static constexpr int BT = 128;                    // term2 tile
static constexpr int NB = N / BT;                 // 64
static constexpr int NTRI = NB * (NB + 1) / 2;    // 2080 triangle blocks

using half8    = __attribute__((ext_vector_type(8))) _Float16;
using floatx16 = __attribute__((ext_vector_type(16))) float;

__device__ __forceinline__ floatx16 zerov() { floatx16 v = {0.f}; return v; }

__device__ __forceinline__ half8 cvt8(float4 v0, float4 v1) {
    half8 h;
    h[0] = (_Float16)v0.x; h[1] = (_Float16)v0.y; h[2] = (_Float16)v0.z; h[3] = (_Float16)v0.w;
    h[4] = (_Float16)v1.x; h[5] = (_Float16)v1.y; h[6] = (_Float16)v1.z; h[7] = (_Float16)v1.w;
    return h;
}

__device__ __forceinline__ float ss8(float4 v0, float4 v1) {
    return v0.x*v0.x + v0.y*v0.y + v0.z*v0.z + v0.w*v0.w
         + v1.x*v1.x + v1.y*v1.y + v1.z*v1.z + v1.w*v1.w;
}

// ---- k_prep: x -> xh (fp16), sq (fp32 from f32 originals), out init -------------------

__launch_bounds__(256)
__global__ void k_prep(const float* __restrict__ x, _Float16* __restrict__ xh,
                       float* __restrict__ sq, float* __restrict__ out) {
    const int tid = threadIdx.x;
    if (blockIdx.x == 0 && tid == 0) out[0] = 0.f;
    const int r = blockIdx.x * 128 + (tid >> 1);
    const int h = tid & 1;                        // thread pair per row, 64 floats each
    const float4* src = (const float4*)(x + (size_t)r * D + h * 64);
    half8* dst = (half8*)(xh + (size_t)r * D + h * 64);
    float ss = 0.f;
#pragma unroll
    for (int i = 0; i < 8; ++i) {
        float4 v0 = src[2 * i], v1 = src[2 * i + 1];
        dst[i] = cvt8(v0, v1);
        ss += ss8(v0, v1);
    }
    ss += __shfl_xor(ss, 1);
    if (h == 0) sq[r] = ss;
}

// ---- k_ap: per-block label scan -> anchor table; ap[j] = D(anchor(lab_j), j) ----------

__launch_bounds__(256)
__global__ void k_ap(const _Float16* __restrict__ xh, const int* __restrict__ labels,
                     const float* __restrict__ sq, int* __restrict__ anchorg,
                     float* __restrict__ ap) {
    __shared__ int sAnc[C];
    const int tid = threadIdx.x;
    for (int i = tid; i < C; i += 256) sAnc[i] = INT_MAX;
    __syncthreads();
    const int4* lab4 = (const int4*)labels;
    for (int t = tid; t < N / 4; t += 256) {
        int4 lv = lab4[t];
        int base = 4 * t;
        atomicMin(&sAnc[lv.x], base);
        atomicMin(&sAnc[lv.y], base + 1);
        atomicMin(&sAnc[lv.z], base + 2);
        atomicMin(&sAnc[lv.w], base + 3);
    }
    __syncthreads();
    if (tid < 8) {                                 // 64 blocks x 8 = 512 anchor slots
        int c = blockIdx.x * 8 + tid;
        int a = sAnc[c];
        anchorg[c] = (a == INT_MAX) ? -1 : a;
    }
    // ap: 2 threads per j (split K), 128 j per block
    const int jj = blockIdx.x * 128 + (tid >> 1);
    const int hk = tid & 1;
    const int lj = labels[jj];
    const int a = sAnc[lj];                        // label present by construction
    const half8* xa = (const half8*)(xh + (size_t)a * D + hk * 64);
    const half8* xj = (const half8*)(xh + (size_t)jj * D + hk * 64);
    float dot = 0.f;
#pragma unroll
    for (int i = 0; i < 8; ++i) {
        half8 va = xa[i], vj = xj[i];
#pragma unroll
        for (int e = 0; e < 8; ++e) dot = fmaf((float)va[e], (float)vj[e], dot);
    }
    dot += __shfl_xor(dot, 1);
    if (hk == 0) ap[jj] = sq[a] + sq[jj] - 2.f * dot;
}

// ---- k_main: term1 (anchor x point, fused e-list hinge) + term2 (point Gram triangle) -
// Barrier-free MFMA: fragments loaded directly from row-major xh (layout matches
// the 32x32x16 A/B fragment: 8 contiguous fp16 at row*D + k + q*8).

__launch_bounds__(256, 2)
__global__ void k_main(const _Float16* __restrict__ xh, const int* __restrict__ labels,
                       const int* __restrict__ anchor, const float* __restrict__ sq,
                       const float* __restrict__ ap, float* __restrict__ out) {
    __shared__ float4 rowE[BT];          // term2: (e2i, labi bits, sq_i, -)
    __shared__ float4 colE[BT];
    __shared__ float sge[FT * MAXG];     // term1: e-lists per class
    __shared__ int   sCnt[FT];
    __shared__ int   sArow[FT];
    __shared__ float sSqA[FT];
    __shared__ float sSqJ[FT];
    __shared__ int   sLabJ[FT];
    __shared__ float wsum[4];

    const int tid = threadIdx.x;
    const int lane = tid & 63, w = tid >> 6;
    const int m = lane & 31, q = lane >> 5;
    float local = 0.f;

    if ((int)blockIdx.x < NT1) {
        // ---------------- term1: 64 classes x 64 points per block ----------------
        const int cb = blockIdx.x >> 7;           // N/FT = 128 j-tiles (2^7)
        const int jb = blockIdx.x & 127;
        const int c0 = cb * FT, j0 = jb * FT;
        const int wrow = (w >> 1) * 32, wcol = (w & 1) * 32;

        if (tid < FT) {
            int a = anchor[c0 + tid];
            int ar = (a < 0) ? 0 : a;             // dummy row for absent class (never used)
            sArow[tid] = ar;
            sSqA[tid] = sq[ar];
            sCnt[tid] = 0;
        } else if (tid < 2 * FT) {
            int j = j0 + tid - FT;
            sLabJ[tid - FT] = labels[j];
            sSqJ[tid - FT] = sq[j];
        }
        __syncthreads();

        // gather e-lists for the 64-class range by scanning labels
        const int4* lab4 = (const int4*)labels;
        for (int t = tid; t < N / 4; t += 256) {
            int4 lv = lab4[t];
            int base = 4 * t;
#pragma unroll
            for (int kk = 0; kk < 4; ++kk) {
                int l = (kk == 0) ? lv.x : (kk == 1) ? lv.y : (kk == 2) ? lv.z : lv.w;
                int li = l - c0;
                if ((unsigned)li < (unsigned)FT) {
                    int idx = base + kk;
                    if (idx != sArow[li]) {       // exclude the anchor itself
                        int slot = atomicAdd(&sCnt[li], 1);
                        if (slot < MAXG) sge[li * MAXG + slot] = ap[idx] + HALFA;
                    }
                }
            }
        }
        __syncthreads();

        // barrier-free MFMA: A = gathered anchor rows, B = point rows
        const int arow = sArow[wrow + m];
        const half8* Apt = (const half8*)(xh + (size_t)arow * D) + q;
        const half8* Bpt = (const half8*)(xh + (size_t)(j0 + wcol + m) * D) + q;
        floatx16 acc = zerov();
#pragma unroll
        for (int k = 0; k < D / 16; ++k) {
            half8 av = Apt[2 * k];
            half8 bv = Bpt[2 * k];
            acc = __builtin_amdgcn_mfma_f32_32x32x16_f16(av, bv, acc, 0, 0, 0);
        }

        const int col = wcol + m;
        const float sqj = sSqJ[col];
        const int labj = sLabJ[col];
#pragma unroll
        for (int rr = 0; rr < 16; ++rr) {
            int row = wrow + (rr & 3) + 8 * (rr >> 2) + 4 * q;
            if (labj != c0 + row) {
                float Dv = fmaf(-2.f, acc[rr], sSqA[row] + sqj);
                int n = sCnt[row]; n = (n > MAXG) ? MAXG : n;
                for (int g = 0; g < n; ++g) {
                    float u = sge[row * MAXG + g] - Dv;   // broadcast read (row uniform per q-half)
                    if (__builtin_fabsf(u) < HALFA) local += u + HALFA;
                }
            }
        }
    } else {
        // ---------------- term2: symmetric point-Gram triangle, 128x128 ----------------
        int rem = blockIdx.x - NT1, br = 0;
        while (rem >= NB - br) { rem -= NB - br; ++br; }
        const int bc = br + rem;
        const int i0 = br * BT, j0 = bc * BT;
        const bool diag = (br == bc);
        const int wr = w >> 1, wc = w & 1;

        if (tid < BT) {
            int i = i0 + tid;
            int li = labels[i];
            int a = anchor[li];
            float sqi = sq[i];
            float e2 = (i == a) ? -1e30f : ap[i] + HALFA - sqi;
            rowE[tid] = make_float4(e2, __int_as_float(li), sqi, 0.f);
        } else {
            int t = tid - BT;
            int j = j0 + t;
            int lj = labels[j];
            int a = anchor[lj];
            float sqj = sq[j];
            float e2 = (j == a) ? -1e30f : ap[j] + HALFA - sqj;
            colE[t] = make_float4(e2, __int_as_float(lj), sqj, 0.f);
        }
        __syncthreads();   // only barrier in the block

        floatx16 acc[2][2];
        acc[0][0] = zerov(); acc[0][1] = zerov(); acc[1][0] = zerov(); acc[1][1] = zerov();

        const half8* A0 = (const half8*)(xh + (size_t)(i0 + wr * 64 + m) * D) + q;
        const half8* A1 = A0 + 32 * (D / 8);
        const half8* B0 = (const half8*)(xh + (size_t)(j0 + wc * 64 + m) * D) + q;
        const half8* B1 = B0 + 32 * (D / 8);
#pragma unroll
        for (int k = 0; k < D / 16; ++k) {
            half8 a0 = A0[2 * k];
            half8 a1 = A1[2 * k];
            half8 b0 = B0[2 * k];
            half8 b1 = B1[2 * k];
            acc[0][0] = __builtin_amdgcn_mfma_f32_32x32x16_f16(a0, b0, acc[0][0], 0, 0, 0);
            acc[0][1] = __builtin_amdgcn_mfma_f32_32x32x16_f16(a0, b1, acc[0][1], 0, 0, 0);
            acc[1][0] = __builtin_amdgcn_mfma_f32_32x32x16_f16(a1, b0, acc[1][0], 0, 0, 0);
            acc[1][1] = __builtin_amdgcn_mfma_f32_32x32x16_f16(a1, b1, acc[1][1], 0, 0, 0);
        }

        float sqjv[2], e2j[2]; int labj[2];
#pragma unroll
        for (int tn = 0; tn < 2; ++tn) {
            float4 cj = colE[wc * 64 + tn * 32 + m];
            e2j[tn] = cj.x; labj[tn] = __float_as_int(cj.y); sqjv[tn] = cj.z;
        }

#pragma unroll
        for (int tm = 0; tm < 2; ++tm) {
            int rbase = wr * 64 + tm * 32 + 4 * q;
#pragma unroll
            for (int rr = 0; rr < 16; ++rr) {
                int row = rbase + (rr & 3) + 8 * (rr >> 2);
                float4 re = rowE[row];
                float e2i = re.x, sqi = re.z;
                int labi = __float_as_int(re.y);
#pragma unroll
                for (int tn = 0; tn < 2; ++tn) {
                    if (labi != labj[tn]) {
                        float dot = acc[tm][tn][rr];
                        float u2 = fmaf(2.f, dot, e2i - sqjv[tn]);
                        if (__builtin_fabsf(u2) < HALFA) local += u2 + HALFA;
                        if (!diag) {
                            float u2b = fmaf(2.f, dot, e2j[tn] - sqi);
                            if (__builtin_fabsf(u2b) < HALFA) local += u2b + HALFA;
                        }
                    }
                }
            }
        }
    }

    // block reduce -> one atomic
#pragma unroll
    for (int off = 32; off; off >>= 1) local += __shfl_down(local, off);
    if (lane == 0) wsum[w] = local;
    __syncthreads();
    if (tid == 0) atomicAdd(out, wsum[0] + wsum[1] + wsum[2] + wsum[3]);
}

// ---------------- launch ----------------

extern "C" void kernel_launch(void* const* d_in, const int* in_sizes, int n_in,
                              void* d_out, int out_size, void* d_ws, size_t ws_size,
                              hipStream_t stream) {
    const float* x = (const float*)d_in[0];
    const int* labels = (const int*)d_in[1];
    float* out = (float*)d_out;

    char* p = (char*)d_ws;
    int* anchor = (int*)p;        p += C * 4;
    float* sq = (float*)p;        p += N * 4;
    float* ap = (float*)p;        p += N * 4;
    p = (char*)(((uintptr_t)p + 255) & ~(uintptr_t)255);
    _Float16* xh = (_Float16*)p;  // N*D*2 = 2 MB

    k_prep<<<N / 128, 256, 0, stream>>>(x, xh, sq, out);
    k_ap<<<N / 128, 256, 0, stream>>>(xh, labels, sq, anchor, ap);
    k_main<<<NT1 + NTRI, 256, 0, stream>>>(xh, labels, anchor, sq, ap, out);
}

// Round 2
// 134.088 us; speedup vs baseline: 1.0616x; 1.0616x over previous
//
#include <hip/hip_runtime.h>
#include <limits.h>
#include <stdint.h>

#define ALPHA 0.2f
#define HALFA 0.1f
static constexpr int N = 8192;
static constexpr int D = 128;
static constexpr int C = 512;
static constexpr int BT = 128;                    // tile edge (both terms)
static constexpr int GR = D / 8;                  // 16 granules (half8) per row
static constexpr int MAXG = 64;                   // e-list capacity (Poisson(16), >8 sigma)
static constexpr int NT1 = (C / BT) * (N / BT);   // 4*64 = 256 term1 blocks
static constexpr int NB = N / BT;                 // 64
static constexpr int NTRI = NB * (NB + 1) / 2;    // 2080 triangle blocks

using half8    = __attribute__((ext_vector_type(8))) _Float16;
using floatx16 = __attribute__((ext_vector_type(16))) float;

__device__ __forceinline__ floatx16 zerov() { floatx16 v = {0.f}; return v; }

__device__ __forceinline__ half8 cvt8(float4 v0, float4 v1) {
    half8 h;
    h[0] = (_Float16)v0.x; h[1] = (_Float16)v0.y; h[2] = (_Float16)v0.z; h[3] = (_Float16)v0.w;
    h[4] = (_Float16)v1.x; h[5] = (_Float16)v1.y; h[6] = (_Float16)v1.z; h[7] = (_Float16)v1.w;
    return h;
}

__device__ __forceinline__ float ss8(float4 v0, float4 v1) {
    return v0.x*v0.x + v0.y*v0.y + v0.z*v0.z + v0.w*v0.w
         + v1.x*v1.x + v1.y*v1.y + v1.z*v1.z + v1.w*v1.w;
}

// ---- k_prep: anchors + xh (fp16) + sq + ap, all in one kernel (64 blocks) -------------
// ap[j] reproduces the proven math: fp32 sq, fp16-rounded dot accumulated in fp32.

__launch_bounds__(256)
__global__ void k_prep(const float* __restrict__ x, const int* __restrict__ labels,
                       _Float16* __restrict__ xh, float* __restrict__ sq,
                       int* __restrict__ anchorg, float* __restrict__ ap,
                       float* __restrict__ out) {
    __shared__ int sAnc[C];
    const int tid = threadIdx.x;
    if (blockIdx.x == 0 && tid == 0) out[0] = 0.f;
    for (int i = tid; i < C; i += 256) sAnc[i] = INT_MAX;
    __syncthreads();
    const int4* lab4 = (const int4*)labels;
    for (int t = tid; t < N / 4; t += 256) {
        int4 lv = lab4[t];
        int base = 4 * t;
        atomicMin(&sAnc[lv.x], base);
        atomicMin(&sAnc[lv.y], base + 1);
        atomicMin(&sAnc[lv.z], base + 2);
        atomicMin(&sAnc[lv.w], base + 3);
    }
    __syncthreads();
    if (tid < 8) {
        int c = blockIdx.x * 8 + tid;
        int a = sAnc[c];
        anchorg[c] = (a == INT_MAX) ? -1 : a;
    }

    // convert own row half, keep fp16 in regs
    const int r = blockIdx.x * 128 + (tid >> 1);
    const int h = tid & 1;
    const float4* src = (const float4*)(x + (size_t)r * D + h * 64);
    half8* dst = (half8*)(xh + (size_t)r * D + h * 64);
    half8 hj[8];
    float ssj = 0.f;
#pragma unroll
    for (int i = 0; i < 8; ++i) {
        float4 v0 = src[2 * i], v1 = src[2 * i + 1];
        hj[i] = cvt8(v0, v1);
        dst[i] = hj[i];
        ssj += ss8(v0, v1);
    }
    ssj += __shfl_xor(ssj, 1);
    if (h == 0) sq[r] = ssj;

    // anchor row: fp32 sq, fp16-rounded dot
    const int a = sAnc[labels[r]];
    const float4* asrc = (const float4*)(x + (size_t)a * D + h * 64);
    float ssa = 0.f, dot = 0.f;
#pragma unroll
    for (int i = 0; i < 8; ++i) {
        float4 a0 = asrc[2 * i], a1 = asrc[2 * i + 1];
        half8 ha = cvt8(a0, a1);
        ssa += ss8(a0, a1);
#pragma unroll
        for (int e = 0; e < 8; ++e) dot = fmaf((float)ha[e], (float)hj[i][e], dot);
    }
    ssa += __shfl_xor(ssa, 1);
    dot += __shfl_xor(dot, 1);
    if (h == 0) ap[r] = ssa + ssj - 2.f * dot;
}

// ---- k_main: term1 (anchor x point tiles, fused e-list hinge) + term2 (Gram triangle) -
// Full-K single-shot LDS staging, K-major granule layout (conflict-free writes & reads),
// ONE barrier before MFMA in term2; term1 adds an e-list gather phase after MFMA.

__launch_bounds__(256, 2)
__global__ void k_main(const _Float16* __restrict__ xh, const int* __restrict__ labels,
                       const int* __restrict__ anchor, const float* __restrict__ sq,
                       const float* __restrict__ ap, float* __restrict__ out) {
    __shared__ __align__(16) _Float16 AsH[GR * BT * 8];   // 32 KB, K-major [granule][row]
    __shared__ __align__(16) _Float16 BsH[GR * BT * 8];   // 32 KB
    __shared__ float4 rowE[BT];
    __shared__ float4 colE[BT];
    __shared__ int   sArow[BT];
    __shared__ float sSqA[BT];
    __shared__ int   sCnt[BT];
    __shared__ float wsum[4];

    half8* As = (half8*)AsH;
    half8* Bs = (half8*)BsH;

    const int tid = threadIdx.x;
    const int lane = tid & 63, w = tid >> 6;
    const int m = lane & 31, q = lane >> 5;
    const int wr = w >> 1, wc = w & 1;
    const int sr = tid & 127, skg = (tid >> 7) * 8;   // staging: row, granule base
    float local = 0.f;

    if ((int)blockIdx.x < NT1) {
        // ---------------- term1: 128 anchors x 128 points ----------------
        const int cb = blockIdx.x >> 6;           // N/BT = 64 j-tiles
        const int jb = blockIdx.x & 63;
        const int c0 = cb * BT, j0 = jb * BT;

        if (tid < BT) {
            int a = anchor[c0 + tid];
            int ar = (a < 0) ? 0 : a;             // dummy row for absent class (never consumed)
            sArow[tid] = ar;
            sSqA[tid] = sq[ar];
            sCnt[tid] = 0;
        } else {
            int j = j0 + tid - BT;
            colE[tid - BT] = make_float4(sq[j], __int_as_float(labels[j]), 0.f, 0.f);
        }
        __syncthreads();

        {   // stage: A = gathered anchor rows, B = point rows (conflict-free ds writes)
            int arow = sArow[sr];
            const half8* sa = (const half8*)(xh + (size_t)arow * D) + skg;
            const half8* sb = (const half8*)(xh + (size_t)(j0 + sr) * D) + skg;
#pragma unroll
            for (int i = 0; i < 8; ++i) {
                As[(skg + i) * BT + sr] = sa[i];
                Bs[(skg + i) * BT + sr] = sb[i];
            }
        }
        __syncthreads();

        floatx16 acc[2][2];
        acc[0][0] = zerov(); acc[0][1] = zerov(); acc[1][0] = zerov(); acc[1][1] = zerov();
#pragma unroll
        for (int k = 0; k < 8; ++k) {
            half8 a0 = As[(2 * k + q) * BT + wr * 64 + m];
            half8 a1 = As[(2 * k + q) * BT + wr * 64 + 32 + m];
            half8 b0 = Bs[(2 * k + q) * BT + wc * 64 + m];
            half8 b1 = Bs[(2 * k + q) * BT + wc * 64 + 32 + m];
            acc[0][0] = __builtin_amdgcn_mfma_f32_32x32x16_f16(a0, b0, acc[0][0], 0, 0, 0);
            acc[0][1] = __builtin_amdgcn_mfma_f32_32x32x16_f16(a0, b1, acc[0][1], 0, 0, 0);
            acc[1][0] = __builtin_amdgcn_mfma_f32_32x32x16_f16(a1, b0, acc[1][0], 0, 0, 0);
            acc[1][1] = __builtin_amdgcn_mfma_f32_32x32x16_f16(a1, b1, acc[1][1], 0, 0, 0);
        }
        __syncthreads();

        // e-list gather into the (now free) A-tile LDS
        float* sge = (float*)AsH;                 // 128 * MAXG * 4B = 32 KB, exact fit
        const int4* lab4 = (const int4*)labels;
        for (int t = tid; t < N / 4; t += 256) {
            int4 lv = lab4[t];
            int base = 4 * t;
#pragma unroll
            for (int kk = 0; kk < 4; ++kk) {
                int l = (kk == 0) ? lv.x : (kk == 1) ? lv.y : (kk == 2) ? lv.z : lv.w;
                int li = l - c0;
                if ((unsigned)li < (unsigned)BT) {
                    int idx = base + kk;
                    if (idx != sArow[li]) {
                        int slot = atomicAdd(&sCnt[li], 1);
                        if (slot < MAXG) sge[li * MAXG + slot] = ap[idx] + HALFA;
                    }
                }
            }
        }
        __syncthreads();

        float sqj[2]; int labj[2];
#pragma unroll
        for (int tn = 0; tn < 2; ++tn) {
            float4 cj = colE[wc * 64 + tn * 32 + m];
            sqj[tn] = cj.x; labj[tn] = __float_as_int(cj.y);
        }
#pragma unroll
        for (int tm = 0; tm < 2; ++tm) {
#pragma unroll
            for (int rr = 0; rr < 16; ++rr) {
                int row = wr * 64 + tm * 32 + (rr & 3) + 8 * (rr >> 2) + 4 * q;
                float sb = sSqA[row];
                float Dv0 = fmaf(-2.f, acc[tm][0][rr], sb + sqj[0]);
                float Dv1 = fmaf(-2.f, acc[tm][1][rr], sb + sqj[1]);
                int cls = c0 + row;
                bool v0 = (labj[0] != cls), v1 = (labj[1] != cls);
                int n = sCnt[row]; n = (n > MAXG) ? MAXG : n;
                for (int g = 0; g < n; ++g) {
                    float e = sge[row * MAXG + g];    // broadcast across lanes
                    float u0 = e - Dv0;
                    if (v0 && __builtin_fabsf(u0) < HALFA) local += u0 + HALFA;
                    float u1 = e - Dv1;
                    if (v1 && __builtin_fabsf(u1) < HALFA) local += u1 + HALFA;
                }
            }
        }
    } else {
        // ---------------- term2: symmetric point-Gram triangle, 128x128 ----------------
        int rem = blockIdx.x - NT1, br = 0;
        while (rem >= NB - br) { rem -= NB - br; ++br; }
        const int bc = br + rem;
        const int i0 = br * BT, j0 = bc * BT;
        const bool diag = (br == bc);

        if (tid < BT) {
            int i = i0 + tid;
            int li = labels[i];
            int a = anchor[li];
            float sqi = sq[i];
            float e2 = (i == a) ? -1e30f : ap[i] + HALFA - sqi;
            rowE[tid] = make_float4(e2, __int_as_float(li), sqi, 0.f);
        } else {
            int t = tid - BT;
            int j = j0 + t;
            int lj = labels[j];
            int a = anchor[lj];
            float sqj = sq[j];
            float e2 = (j == a) ? -1e30f : ap[j] + HALFA - sqj;
            colE[t] = make_float4(e2, __int_as_float(lj), sqj, 0.f);
        }

        {   // stage both tiles (K-major)
            const half8* sa = (const half8*)(xh + (size_t)(i0 + sr) * D) + skg;
            const half8* sb = (const half8*)(xh + (size_t)(j0 + sr) * D) + skg;
#pragma unroll
            for (int i = 0; i < 8; ++i) {
                As[(skg + i) * BT + sr] = sa[i];
                Bs[(skg + i) * BT + sr] = sb[i];
            }
        }
        __syncthreads();   // the only barrier before the reduce

        floatx16 acc[2][2];
        acc[0][0] = zerov(); acc[0][1] = zerov(); acc[1][0] = zerov(); acc[1][1] = zerov();
#pragma unroll
        for (int k = 0; k < 8; ++k) {
            half8 a0 = As[(2 * k + q) * BT + wr * 64 + m];
            half8 a1 = As[(2 * k + q) * BT + wr * 64 + 32 + m];
            half8 b0 = Bs[(2 * k + q) * BT + wc * 64 + m];
            half8 b1 = Bs[(2 * k + q) * BT + wc * 64 + 32 + m];
            acc[0][0] = __builtin_amdgcn_mfma_f32_32x32x16_f16(a0, b0, acc[0][0], 0, 0, 0);
            acc[0][1] = __builtin_amdgcn_mfma_f32_32x32x16_f16(a0, b1, acc[0][1], 0, 0, 0);
            acc[1][0] = __builtin_amdgcn_mfma_f32_32x32x16_f16(a1, b0, acc[1][0], 0, 0, 0);
            acc[1][1] = __builtin_amdgcn_mfma_f32_32x32x16_f16(a1, b1, acc[1][1], 0, 0, 0);
        }

        float sqjv[2], e2j[2]; int labj[2];
#pragma unroll
        for (int tn = 0; tn < 2; ++tn) {
            float4 cj = colE[wc * 64 + tn * 32 + m];
            e2j[tn] = cj.x; labj[tn] = __float_as_int(cj.y); sqjv[tn] = cj.z;
        }
#pragma unroll
        for (int tm = 0; tm < 2; ++tm) {
            int rbase = wr * 64 + tm * 32 + 4 * q;
#pragma unroll
            for (int rr = 0; rr < 16; ++rr) {
                int row = rbase + (rr & 3) + 8 * (rr >> 2);
                float4 re = rowE[row];
                float e2i = re.x, sqi = re.z;
                int labi = __float_as_int(re.y);
#pragma unroll
                for (int tn = 0; tn < 2; ++tn) {
                    if (labi != labj[tn]) {
                        float dot = acc[tm][tn][rr];
                        float u2 = fmaf(2.f, dot, e2i - sqjv[tn]);
                        if (__builtin_fabsf(u2) < HALFA) local += u2 + HALFA;
                        if (!diag) {
                            float u2b = fmaf(2.f, dot, e2j[tn] - sqi);
                            if (__builtin_fabsf(u2b) < HALFA) local += u2b + HALFA;
                        }
                    }
                }
            }
        }
    }

    // block reduce -> one atomic
#pragma unroll
    for (int off = 32; off; off >>= 1) local += __shfl_down(local, off);
    if (lane == 0) wsum[w] = local;
    __syncthreads();
    if (tid == 0) atomicAdd(out, wsum[0] + wsum[1] + wsum[2] + wsum[3]);
}

// ---------------- launch ----------------

extern "C" void kernel_launch(void* const* d_in, const int* in_sizes, int n_in,
                              void* d_out, int out_size, void* d_ws, size_t ws_size,
                              hipStream_t stream) {
    const float* x = (const float*)d_in[0];
    const int* labels = (const int*)d_in[1];
    float* out = (float*)d_out;

    char* p = (char*)d_ws;
    int* anchor = (int*)p;        p += C * 4;
    float* sq = (float*)p;        p += N * 4;
    float* ap = (float*)p;        p += N * 4;
    p = (char*)(((uintptr_t)p + 255) & ~(uintptr_t)255);
    _Float16* xh = (_Float16*)p;  // N*D*2 = 2 MB

    k_prep<<<N / 128, 256, 0, stream>>>(x, labels, xh, sq, anchor, ap, out);
    k_main<<<NT1 + NTRI, 256, 0, stream>>>(xh, labels, anchor, sq, ap, out);
}

// Round 3
// 110.109 us; speedup vs baseline: 1.2928x; 1.2178x over previous
//
#include <hip/hip_runtime.h>
#include <limits.h>
#include <stdint.h>

#define ALPHA 0.2f
#define HALFA 0.1f
static constexpr int N = 8192;
static constexpr int D = 128;
static constexpr int C = 512;
static constexpr int BT = 128;                    // tile edge (both terms)
static constexpr int GR = D / 8;                  // 16 granules (half8) per row
static constexpr int SL = BT + 1;                 // padded rows per granule (bank decorrelation)
static constexpr int MAXG = 64;                   // e-list capacity (Binomial mean 16, >8 sigma)
static constexpr int NT1 = (C / BT) * (N / BT);   // 4*64 = 256 term1 blocks
static constexpr int NB = N / BT;                 // 64
static constexpr int NTRI = NB * (NB + 1) / 2;    // 2080 triangle blocks

using half8    = __attribute__((ext_vector_type(8))) _Float16;
using floatx16 = __attribute__((ext_vector_type(16))) float;

__device__ __forceinline__ floatx16 zerov() { floatx16 v = {0.f}; return v; }

__device__ __forceinline__ half8 cvt8(float4 v0, float4 v1) {
    half8 h;
    h[0] = (_Float16)v0.x; h[1] = (_Float16)v0.y; h[2] = (_Float16)v0.z; h[3] = (_Float16)v0.w;
    h[4] = (_Float16)v1.x; h[5] = (_Float16)v1.y; h[6] = (_Float16)v1.z; h[7] = (_Float16)v1.w;
    return h;
}

__device__ __forceinline__ float ss8(float4 v0, float4 v1) {
    return v0.x*v0.x + v0.y*v0.y + v0.z*v0.z + v0.w*v0.w
         + v1.x*v1.x + v1.y*v1.y + v1.z*v1.z + v1.w*v1.w;
}

// ---- k_prep: anchors + xh (fp16) + sq + ap. 256 blocks x 256 thr, 32 rows/block -------

__launch_bounds__(256)
__global__ void k_prep(const float* __restrict__ x, const int* __restrict__ labels,
                       _Float16* __restrict__ xh, float* __restrict__ sq,
                       int* __restrict__ anchorg, float* __restrict__ ap,
                       float* __restrict__ out) {
    __shared__ int sAnc[C];
    const int tid = threadIdx.x;
    if (blockIdx.x == 0 && tid == 0) out[0] = 0.f;
    for (int i = tid; i < C; i += 256) sAnc[i] = INT_MAX;
    __syncthreads();
    const int4* lab4 = (const int4*)labels;
    for (int t = tid; t < N / 4; t += 256) {
        int4 lv = lab4[t];
        int base = 4 * t;
        atomicMin(&sAnc[lv.x], base);
        atomicMin(&sAnc[lv.y], base + 1);
        atomicMin(&sAnc[lv.z], base + 2);
        atomicMin(&sAnc[lv.w], base + 3);
    }
    __syncthreads();
    if (tid < 2) {
        int c = blockIdx.x * 2 + tid;
        int a = sAnc[c];
        anchorg[c] = (a == INT_MAX) ? -1 : a;
    }

    // 8 threads per row, 16 floats (2 granules) each
    const int r = blockIdx.x * 32 + (tid >> 3);
    const int sub = tid & 7;
    const float4* src = (const float4*)(x + (size_t)r * D) + sub * 4;
    half8* dst = (half8*)(xh + (size_t)r * D) + sub * 2;
    half8 hj[2];
    float ssj = 0.f;
#pragma unroll
    for (int i = 0; i < 2; ++i) {
        float4 v0 = src[2 * i], v1 = src[2 * i + 1];
        hj[i] = cvt8(v0, v1);
        dst[i] = hj[i];
        ssj += ss8(v0, v1);
    }
    ssj += __shfl_xor(ssj, 1); ssj += __shfl_xor(ssj, 2); ssj += __shfl_xor(ssj, 4);

    // anchor row of this row's label: fp32 sq, fp16-rounded dot (same math as before)
    const int a = sAnc[labels[r]];
    const float4* asrc = (const float4*)(x + (size_t)a * D) + sub * 4;
    float ssa = 0.f, dot = 0.f;
#pragma unroll
    for (int i = 0; i < 2; ++i) {
        float4 a0 = asrc[2 * i], a1 = asrc[2 * i + 1];
        half8 ha = cvt8(a0, a1);
        ssa += ss8(a0, a1);
#pragma unroll
        for (int e = 0; e < 8; ++e) dot = fmaf((float)ha[e], (float)hj[i][e], dot);
    }
    ssa += __shfl_xor(ssa, 1); ssa += __shfl_xor(ssa, 2); ssa += __shfl_xor(ssa, 4);
    dot += __shfl_xor(dot, 1); dot += __shfl_xor(dot, 2); dot += __shfl_xor(dot, 4);
    if (sub == 0) {
        sq[r] = ssj;
        ap[r] = ssa + ssj - 2.f * dot;
    }
}

// ---- k_main: 512 thr / 8 waves. A-operand in registers (direct global), B in LDS ------
// K-major padded LDS layout: granule g, row r at Bs[g*SL + r] (SL=129) -> conflict-free
// ds_write_b128 (4*(g+r) mod 32 spreads 8 lanes/bank-group) and contiguous ds_read.

__launch_bounds__(512, 4)
__global__ void k_main(const _Float16* __restrict__ xh, const int* __restrict__ labels,
                       const int* __restrict__ anchor, const float* __restrict__ sq,
                       const float* __restrict__ ap, float* __restrict__ out) {
    __shared__ __align__(16) _Float16 BsH[GR * SL * 8];   // 33 KB
    __shared__ float4 rowE[BT];
    __shared__ float4 colE[BT];
    __shared__ int   sArow[BT];
    __shared__ float sSqA[BT];
    __shared__ int   sCnt[BT];
    __shared__ float wsum[8];
    half8* Bs = (half8*)BsH;

    const int tid = threadIdx.x;
    const int lane = tid & 63, w = tid >> 6;          // 8 waves
    const int m = lane & 31, q = lane >> 5;
    const int wr = w >> 1, wc = w & 1;                // row-group 0..3 (32 rows), col-group 0..1 (64 cols)
    const int sg = tid & 15, sr0 = tid >> 4;          // staging: granule, row base (coalesced)
    float local = 0.f;

    if ((int)blockIdx.x < NT1) {
        // ---------------- term1: 128 anchors x 128 points ----------------
        const int cb = blockIdx.x >> 6;
        const int jb = blockIdx.x & 63;
        const int c0 = cb * BT, j0 = jb * BT;

        if (tid < BT) {
            int a = anchor[c0 + tid];
            int ar = (a < 0) ? 0 : a;                 // dummy for absent class (never contributes)
            sArow[tid] = ar;
            sSqA[tid] = sq[ar];
            sCnt[tid] = 0;
        } else if (tid < 2 * BT) {
            int j = j0 + tid - BT;
            colE[tid - BT] = make_float4(sq[j], __int_as_float(labels[j]), 0.f, 0.f);
        }
        __syncthreads();

        // A fragments -> registers (gathered anchor rows); latency hides under B staging
        const int arow = sArow[wr * 32 + m];
        const half8* aptr = (const half8*)(xh + (size_t)arow * D) + q;
        half8 af[8];
#pragma unroll
        for (int k = 0; k < 8; ++k) af[k] = aptr[2 * k];

        // stage B (point rows): coalesced global reads, conflict-free ds writes
#pragma unroll
        for (int i = 0; i < 4; ++i) {
            int row = sr0 + i * 32;
            Bs[sg * SL + row] = *((const half8*)(xh + (size_t)(j0 + row) * D) + sg);
        }
        __syncthreads();

        floatx16 acc0 = zerov(), acc1 = zerov();
#pragma unroll
        for (int k = 0; k < 8; ++k) {
            half8 b0 = Bs[(2 * k + q) * SL + wc * 64 + m];
            half8 b1 = Bs[(2 * k + q) * SL + wc * 64 + 32 + m];
            acc0 = __builtin_amdgcn_mfma_f32_32x32x16_f16(af[k], b0, acc0, 0, 0, 0);
            acc1 = __builtin_amdgcn_mfma_f32_32x32x16_f16(af[k], b1, acc1, 0, 0, 0);
        }
        __syncthreads();

        // e-list gather into the (now free) B-tile LDS
        float* sge = (float*)BsH;                      // 128*64*4 = 32 KB <= 33 KB
        const int4* lab4 = (const int4*)labels;
        for (int t = tid; t < N / 4; t += 512) {
            int4 lv = lab4[t];
            int base = 4 * t;
#pragma unroll
            for (int kk = 0; kk < 4; ++kk) {
                int l = (kk == 0) ? lv.x : (kk == 1) ? lv.y : (kk == 2) ? lv.z : lv.w;
                int li = l - c0;
                if ((unsigned)li < (unsigned)BT) {
                    int idx = base + kk;
                    if (idx != sArow[li]) {
                        int slot = atomicAdd(&sCnt[li], 1);
                        if (slot < MAXG) sge[li * MAXG + slot] = ap[idx] + HALFA;
                    }
                }
            }
        }
        __syncthreads();

        float sqj0, sqj1; int labj0, labj1;
        { float4 cj = colE[wc * 64 + m];      sqj0 = cj.x; labj0 = __float_as_int(cj.y); }
        { float4 cj = colE[wc * 64 + 32 + m]; sqj1 = cj.x; labj1 = __float_as_int(cj.y); }
#pragma unroll
        for (int rr = 0; rr < 16; ++rr) {
            int row = wr * 32 + (rr & 3) + 8 * (rr >> 2) + 4 * q;
            float sa = sSqA[row];
            int cls = c0 + row;
            float Dv0 = fmaf(-2.f, acc0[rr], sa + sqj0);
            float Dv1 = fmaf(-2.f, acc1[rr], sa + sqj1);
            bool v0 = (labj0 != cls), v1 = (labj1 != cls);
            int n = sCnt[row]; n = (n > MAXG) ? MAXG : n;
            for (int g = 0; g < n; ++g) {
                float e = sge[row * MAXG + g];         // broadcast within each q-half
                float u0 = e - Dv0;
                if (v0 && __builtin_fabsf(u0) < HALFA) local += u0 + HALFA;
                float u1 = e - Dv1;
                if (v1 && __builtin_fabsf(u1) < HALFA) local += u1 + HALFA;
            }
        }
    } else {
        // ---------------- term2: symmetric point-Gram triangle, 128x128 ----------------
        int rem = blockIdx.x - NT1, br = 0;
        while (rem >= NB - br) { rem -= NB - br; ++br; }
        const int bc = br + rem;
        const int i0 = br * BT, j0 = bc * BT;
        const bool diag = (br == bc);

        if (tid < BT) {
            int i = i0 + tid;
            int li = labels[i];
            int a = anchor[li];
            float sqi = sq[i];
            float e2 = (i == a) ? -1e30f : ap[i] + HALFA - sqi;
            rowE[tid] = make_float4(e2, __int_as_float(li), sqi, 0.f);
        } else if (tid < 2 * BT) {
            int t = tid - BT;
            int j = j0 + t;
            int lj = labels[j];
            int a = anchor[lj];
            float sqj = sq[j];
            float e2 = (j == a) ? -1e30f : ap[j] + HALFA - sqj;
            colE[t] = make_float4(e2, __int_as_float(lj), sqj, 0.f);
        }

        // A fragments -> registers (contiguous rows, no LDS round-trip)
        const half8* aptr = (const half8*)(xh + (size_t)(i0 + wr * 32 + m) * D) + q;
        half8 af[8];
#pragma unroll
        for (int k = 0; k < 8; ++k) af[k] = aptr[2 * k];

        // stage B
#pragma unroll
        for (int i = 0; i < 4; ++i) {
            int row = sr0 + i * 32;
            Bs[sg * SL + row] = *((const half8*)(xh + (size_t)(j0 + row) * D) + sg);
        }
        __syncthreads();   // the only barrier before the reduce

        floatx16 acc0 = zerov(), acc1 = zerov();
#pragma unroll
        for (int k = 0; k < 8; ++k) {
            half8 b0 = Bs[(2 * k + q) * SL + wc * 64 + m];
            half8 b1 = Bs[(2 * k + q) * SL + wc * 64 + 32 + m];
            acc0 = __builtin_amdgcn_mfma_f32_32x32x16_f16(af[k], b0, acc0, 0, 0, 0);
            acc1 = __builtin_amdgcn_mfma_f32_32x32x16_f16(af[k], b1, acc1, 0, 0, 0);
        }

        float sqjv[2], e2j[2]; int labj[2];
        { float4 cj = colE[wc * 64 + m];      e2j[0] = cj.x; labj[0] = __float_as_int(cj.y); sqjv[0] = cj.z; }
        { float4 cj = colE[wc * 64 + 32 + m]; e2j[1] = cj.x; labj[1] = __float_as_int(cj.y); sqjv[1] = cj.z; }

#pragma unroll
        for (int rr = 0; rr < 16; ++rr) {
            int row = wr * 32 + (rr & 3) + 8 * (rr >> 2) + 4 * q;
            float4 re = rowE[row];
            float e2i = re.x, sqi = re.z;
            int labi = __float_as_int(re.y);
            {
                float dot = acc0[rr];
                if (labi != labj[0]) {
                    float u2 = fmaf(2.f, dot, e2i - sqjv[0]);
                    if (__builtin_fabsf(u2) < HALFA) local += u2 + HALFA;
                    if (!diag) {
                        float u2b = fmaf(2.f, dot, e2j[0] - sqi);
                        if (__builtin_fabsf(u2b) < HALFA) local += u2b + HALFA;
                    }
                }
            }
            {
                float dot = acc1[rr];
                if (labi != labj[1]) {
                    float u2 = fmaf(2.f, dot, e2i - sqjv[1]);
                    if (__builtin_fabsf(u2) < HALFA) local += u2 + HALFA;
                    if (!diag) {
                        float u2b = fmaf(2.f, dot, e2j[1] - sqi);
                        if (__builtin_fabsf(u2b) < HALFA) local += u2b + HALFA;
                    }
                }
            }
        }
    }

    // block reduce -> one atomic
#pragma unroll
    for (int off = 32; off; off >>= 1) local += __shfl_down(local, off);
    if (lane == 0) wsum[w] = local;
    __syncthreads();
    if (tid == 0) {
        float s = 0.f;
#pragma unroll
        for (int i = 0; i < 8; ++i) s += wsum[i];
        atomicAdd(out, s);
    }
}

// ---------------- launch ----------------

extern "C" void kernel_launch(void* const* d_in, const int* in_sizes, int n_in,
                              void* d_out, int out_size, void* d_ws, size_t ws_size,
                              hipStream_t stream) {
    const float* x = (const float*)d_in[0];
    const int* labels = (const int*)d_in[1];
    float* out = (float*)d_out;

    char* p = (char*)d_ws;
    int* anchor = (int*)p;        p += C * 4;
    float* sq = (float*)p;        p += N * 4;
    float* ap = (float*)p;        p += N * 4;
    p = (char*)(((uintptr_t)p + 255) & ~(uintptr_t)255);
    _Float16* xh = (_Float16*)p;  // N*D*2 = 2 MB

    k_prep<<<N / 32, 256, 0, stream>>>(x, labels, xh, sq, anchor, ap, out);
    k_main<<<NT1 + NTRI, 512, 0, stream>>>(xh, labels, anchor, sq, ap, out);
}